// Round 8
// baseline (355.694 us; speedup 1.0000x reference)
//
#include <hip/hip_runtime.h>
#include <stdint.h>

typedef unsigned short u16;
typedef __bf16 bf16x8 __attribute__((ext_vector_type(8)));
typedef float f32x4 __attribute__((ext_vector_type(4)));
typedef float f32x2 __attribute__((ext_vector_type(2)));
typedef u16 u16x4v __attribute__((ext_vector_type(4)));

#define DI __device__ __forceinline__

constexpr int BB = 2, SS = 2048, EE = 1024, HH = 16, DD = 64;
constexpr int MROWS = BB * SS;   // 4096 tokens
constexpr int KDIM = 1024, NDIM = 1024;

DI u16 f2bf(float f) {  // RNE float->bf16 (finite inputs)
  uint32_t u = __float_as_uint(f);
  return (u16)((u + 0x7FFFu + ((u >> 16) & 1u)) >> 16);
}
DI float bf2f(u16 h) { return __uint_as_float(((uint32_t)h) << 16); }

DI uint32_t cvtpk_bf16(float a, float b) {  // low=bf16(a), high=bf16(b), RNE
  uint32_t r;
  asm("v_cvt_pk_bf16_f32 %0, %1, %2" : "=v"(r) : "v"(a), "v"(b));
  return r;
}

DI void cp16(const void* g, void* lds) {
  __builtin_amdgcn_global_load_lds((const __attribute__((address_space(1))) void*)g,
                                   (__attribute__((address_space(3))) void*)lds, 16, 0, 0);
}

DI f32x4 mfma16(bf16x8 a, bf16x8 b, f32x4 c) {
  return __builtin_amdgcn_mfma_f32_16x16x32_bf16(a, b, c, 0, 0, 0);
}

// ---------------- prep: fp32 -> bf16 casts + RoPE table (merged) ------------
__global__ __launch_bounds__(256) void prep_cast(
    const float* __restrict__ q, const float* __restrict__ k, const float* __restrict__ v,
    const float* __restrict__ wq, const float* __restrict__ wk, const float* __restrict__ wv,
    const float* __restrict__ wo,
    u16* __restrict__ qb, u16* __restrict__ kb, u16* __restrict__ vb,
    u16* __restrict__ wqb, u16* __restrict__ wkb, u16* __restrict__ wvb,
    u16* __restrict__ wob, float* __restrict__ csT) {
  constexpr size_t SZI = (size_t)MROWS * EE;  // 4M
  constexpr size_t SZW = (size_t)EE * EE;     // 1M
  if (blockIdx.x >= 16384) {
    // RoPE table: csT[s][d] = {cos, sin}
    const int t = (blockIdx.x - 16384) * 256 + threadIdx.x;   // < 2048*64
    const int s = t >> 6, d = t & 63, j = d & 31;
    const float ang = (float)s * exp2f(-(float)j * 0.4152410118f);
    float2 cs; cs.x = cosf(ang); cs.y = sinf(ang);
    ((float2*)csT)[t] = cs;
    return;
  }
  const size_t g = ((size_t)blockIdx.x * 256 + threadIdx.x) * 4;
  const float* src; u16* dst; size_t o;
  if (g < SZI)          { src = q; dst = qb; o = g; }
  else if (g < 2 * SZI) { src = k; dst = kb; o = g - SZI; }
  else if (g < 3 * SZI) { src = v; dst = vb; o = g - 2 * SZI; }
  else {
    size_t t2 = g - 3 * SZI;
    int wi = (int)(t2 / SZW);
    o = t2 - (size_t)wi * SZW;
    src = wi == 0 ? wq : wi == 1 ? wk : wi == 2 ? wv : wo;
    dst = wi == 0 ? wqb : wi == 1 ? wkb : wi == 2 ? wvb : wob;
  }
  const float4 f = *(const float4*)(src + o);
  u16x4v hv;
  hv[0] = f2bf(f.x); hv[1] = f2bf(f.y); hv[2] = f2bf(f.z); hv[3] = f2bf(f.w);
  *(u16x4v*)(dst + o) = hv;
}

// ---------------- QKV projection GEMM, BK=64 ----------------
// Q/K: A = W (m=feat), B = X (n=token), RoPE in-register.
// V  : A = X (m=token), B = Wv (n=feat); Vtg keys pi-permuted in 32-groups.
__global__ __launch_bounds__(256) void gemm_qkv(
    const u16* __restrict__ qb, const u16* __restrict__ kb, const u16* __restrict__ vb,
    const u16* __restrict__ wqb, const u16* __restrict__ wkb, const u16* __restrict__ wvb,
    const float* __restrict__ bq, const float* __restrict__ bk, const float* __restrict__ bv,
    u16* __restrict__ Qp, u16* __restrict__ Kp, u16* __restrict__ Vtg,
    const float* __restrict__ csT) {
  __shared__ alignas(16) u16 sA[128 * 64];
  __shared__ alignas(16) u16 sB[128 * 64];
  const int tsel = blockIdx.y >> 5;  // 0=Q 1=K 2=V
  const bool vtr = (tsel == 2);
  const u16* A    = tsel == 0 ? wqb : tsel == 1 ? wkb : vb;
  const u16* Bm   = tsel == 0 ? qb  : tsel == 1 ? kb  : wvb;
  const float* bias = tsel == 0 ? bq : tsel == 1 ? bk : bv;

  const int fBase = blockIdx.x * 128;          // feature block (8)
  const int tBase = (blockIdx.y & 31) * 128;   // token block (32)
  const int aBase = vtr ? tBase : fBase;
  const int bBase = vtr ? fBase : tBase;
  const int tid = threadIdx.x;
  const int lane = tid & 63, w = tid >> 6;
  const int quad = lane >> 4, l16 = lane & 15;
  const int wr = w >> 1, wc = w & 1;

  size_t aSrc[4], bSrc[4];
  u16 *aDst[4], *bDst[4];
#pragma unroll
  for (int j = 0; j < 4; ++j) {
    const int c = tid + j * 256;
    const int row = c >> 3, sl = c & 7;
    const size_t off = (size_t)row * KDIM + ((sl ^ (row & 7)) * 8);
    aSrc[j] = (size_t)aBase * KDIM + off; aDst[j] = &sA[c * 8];
    bSrc[j] = (size_t)bBase * KDIM + off; bDst[j] = &sB[c * 8];
  }

  f32x4 acc[4][4];
#pragma unroll
  for (int mi = 0; mi < 4; ++mi)
#pragma unroll
    for (int ni = 0; ni < 4; ++ni)
#pragma unroll
      for (int e = 0; e < 4; ++e) acc[mi][ni][e] = 0.f;

  const int arow = wr * 64 + l16, brow = wc * 64 + l16;

  for (int k0 = 0; k0 < KDIM; k0 += 64) {
    __syncthreads();
#pragma unroll
    for (int j = 0; j < 4; ++j) {
      cp16(A + aSrc[j] + k0, aDst[j]);
      cp16(Bm + bSrc[j] + k0, bDst[j]);
    }
    __syncthreads();
#pragma unroll
    for (int h = 0; h < 2; ++h) {
      bf16x8 af[4], bf[4];
#pragma unroll
      for (int i = 0; i < 4; ++i) {
        const int ar = arow + i * 16, br = brow + i * 16;
        af[i] = *(const bf16x8*)&sA[ar * 64 + (((h * 4 + quad) ^ (ar & 7)) << 3)];
        bf[i] = *(const bf16x8*)&sB[br * 64 + (((h * 4 + quad) ^ (br & 7)) << 3)];
      }
#pragma unroll
      for (int mi = 0; mi < 4; ++mi)
#pragma unroll
        for (int ni = 0; ni < 4; ++ni)
          acc[mi][ni] = mfma16(af[mi], bf[ni], acc[mi][ni]);
    }
  }

  if (!vtr) {
    u16* C = tsel == 0 ? Qp : Kp;
#pragma unroll
    for (int mi = 0; mi < 4; ++mi) {
      const int fm = fBase + wr * 64 + mi * 16 + quad * 4;
      const float4 b4 = *(const float4*)&bias[fm];
      const int d0 = fm & 63;
#pragma unroll
      for (int ni = 0; ni < 4; ++ni) {
        const int t = tBase + wc * 64 + ni * 16 + l16;
        const int srow = t & (SS - 1);
        const float* cs = &csT[(size_t)((srow << 6) + d0) * 2];
        const float4 cs01 = *(const float4*)cs;
        const float4 cs23 = *(const float4*)(cs + 4);
        const float v0 = acc[mi][ni][0] + b4.x;
        const float v1 = acc[mi][ni][1] + b4.y;
        const float v2 = acc[mi][ni][2] + b4.z;
        const float v3 = acc[mi][ni][3] + b4.w;
        const float o0 = v0 * cs01.x - v1 * cs01.y;
        const float o1 = v1 * cs01.z + v0 * cs01.w;
        const float o2 = v2 * cs23.x - v3 * cs23.y;
        const float o3 = v3 * cs23.z + v2 * cs23.w;
        uint2 pk;
        pk.x = cvtpk_bf16(o0, o1);
        pk.y = cvtpk_bf16(o2, o3);
        *(uint2*)&C[(size_t)t * NDIM + fm] = pk;
      }
    }
  } else {
#pragma unroll
    for (int ni = 0; ni < 4; ++ni) {
      const int f = fBase + wc * 64 + ni * 16 + l16;
      const int h = f >> 6, d = f & 63;
      const float bb = bias[f];
#pragma unroll
      for (int mi = 0; mi < 4; ++mi) {
        const int t0 = tBase + wr * 64 + mi * 16 + quad * 4;
        const int b = t0 >> 11, s0 = t0 & (SS - 1);
        const int sp0 = (s0 & ~31) | (((s0 >> 2) & 3) << 3) | (((s0 >> 4) & 1) << 2);
        uint2 pk;
        pk.x = cvtpk_bf16(acc[mi][ni][0] + bb, acc[mi][ni][1] + bb);
        pk.y = cvtpk_bf16(acc[mi][ni][2] + bb, acc[mi][ni][3] + bb);
        *(uint2*)&Vtg[((size_t)((b * 16 + h) * 64 + d)) * SS + sp0] = pk;
      }
    }
  }
}

// ---------------- flash attention: split-K halves, fixed-max softmax --------
// 512 threads = 8 waves, Q-tile 128; blockIdx.x = bh (XCD-clustered),
// blockIdx.y = qtile*2 + khalf. Each block does 8 of 16 key-tiles, writes
// partial O (bf16, unnormalized) + partial l (fp32). Fixed-max softmax makes
// the cross-half combine linear (no max exchange).
__global__ __launch_bounds__(512, 8) void attn_kernel(
    const u16* __restrict__ Qp, const u16* __restrict__ Kp, const u16* __restrict__ Vtg,
    const int* __restrict__ mask, u16* __restrict__ Op, float* __restrict__ lp) {
  __shared__ alignas(16) u16 sK[128 * 64];    // [key][d], swizzled
  __shared__ alignas(16) u16 sVt[64 * 128];   // [d][slot], swizzled
  __shared__ float sMask[128];
  const int tid = threadIdx.x, lane = tid & 63, w = tid >> 6;
  const int quad = lane >> 4, l16 = lane & 15;
  const int bh = blockIdx.x, b = bh >> 4, h = bh & 15;
  const int khalf = blockIdx.y & 1, qt = blockIdx.y >> 1;
  const int q0 = qt * 128 + w * 16;
  const u16* Qb = Qp + (size_t)b * SS * EE + h * DD;
  const u16* Kb = Kp + (size_t)b * SS * EE + h * DD;
  const u16* Vb = Vtg + (size_t)bh * DD * SS;
  constexpr float C1 = 0.18033688011112042f;   // (1/sqrt(64)) * log2(e)
  constexpr float FM = 12.0f;                  // fixed max offset (log2 domain)
  constexpr float MNEG = -30000.f;

  bf16x8 qf[2];
#pragma unroll
  for (int ks = 0; ks < 2; ++ks)
    qf[ks] = *(const bf16x8*)(Qb + (size_t)(q0 + l16) * EE + ks * 32 + quad * 8);

  f32x4 oacc[4];
#pragma unroll
  for (int nd = 0; nd < 4; ++nd)
#pragma unroll
    for (int e = 0; e < 4; ++e) oacc[nd][e] = 0.f;
  f32x2 sum2 = {0.f, 0.f};

  for (int kt = khalf * 8; kt < khalf * 8 + 8; ++kt) {
    const int key0 = kt * 128;
    __syncthreads();
#pragma unroll
    for (int i = 0; i < 2; ++i) {
      const int c = i * 512 + tid;
      const int key = c >> 3;
      const int g8 = ((c & 7) ^ (key & 7)) * 8;
      cp16(Kb + (size_t)(key0 + key) * EE + g8, &sK[c * 8]);
    }
#pragma unroll
    for (int i = 0; i < 2; ++i) {
      const int L = i * 512 + tid;
      const int d = L >> 4;
      const int g8 = ((L & 15) ^ (d & 15)) * 8;
      cp16(Vb + (size_t)d * SS + key0 + g8, &sVt[L * 8]);
    }
    if (tid < 128) sMask[tid] = mask[b * SS + key0 + tid] ? -FM : MNEG;
    __syncthreads();

    // S^T = K * Q^T : D[m=key][n=q]
    f32x4 sacc[8];
#pragma unroll
    for (int ni = 0; ni < 8; ++ni)
#pragma unroll
      for (int e = 0; e < 4; ++e) sacc[ni][e] = 0.f;
#pragma unroll
    for (int ks = 0; ks < 2; ++ks)
#pragma unroll
      for (int ni = 0; ni < 8; ++ni) {
        const int row = ni * 16 + l16;
        const bf16x8 kf = *(const bf16x8*)&sK[row * 64 + (((ks * 4 + quad) ^ (l16 & 7)) << 3)];
        sacc[ni] = mfma16(kf, qf[ks], sacc[ni]);
      }

    // single-pass softmax: p = exp2(s*C1 + mval)
    uint32_t pw32[4][4];
#pragma unroll
    for (int ni = 0; ni < 8; ++ni) {
      const int kb4 = ni * 16 + quad * 4;
      const f32x2 m01 = *(const f32x2*)&sMask[kb4];
      const f32x2 m23 = *(const f32x2*)&sMask[kb4 + 2];
      f32x2 t01, t23;
      t01.x = sacc[ni][0]; t01.y = sacc[ni][1];
      t23.x = sacc[ni][2]; t23.y = sacc[ni][3];
      t01 = t01 * C1 + m01;
      t23 = t23 * C1 + m23;
      f32x2 p01, p23;
      p01.x = exp2f(t01.x); p01.y = exp2f(t01.y);
      p23.x = exp2f(t23.x); p23.y = exp2f(t23.y);
      sum2 += p01;
      sum2 += p23;
      const int k2 = ni >> 1, j2 = (ni & 1) * 2;
      pw32[k2][j2]     = cvtpk_bf16(p01.x, p01.y);
      pw32[k2][j2 + 1] = cvtpk_bf16(p23.x, p23.y);
    }

    // O += P @ V  (K=32, pi-permuted key order on both operands)
#pragma unroll
    for (int k2 = 0; k2 < 4; ++k2) {
      union { uint32_t u[4]; bf16x8 v; } pf;
#pragma unroll
      for (int j = 0; j < 4; ++j) pf.u[j] = pw32[k2][j];
#pragma unroll
      for (int nd = 0; nd < 4; ++nd) {
        const int row = nd * 16 + l16;
        const bf16x8 vf = *(const bf16x8*)&sVt[row * 128 + (((k2 * 4 + quad) ^ l16) << 3)];
        oacc[nd] = mfma16(pf.v, vf, oacc[nd]);
      }
    }
  }

  // partial l: combine across quads (disjoint key subsets, same q=l16)
  float lrow = sum2.x + sum2.y;
  lrow += __shfl_xor(lrow, 16, 64);
  lrow += __shfl_xor(lrow, 32, 64);
  if (lane < 16)
    lp[(size_t)khalf * (BB * HH * SS) + (size_t)bh * SS + q0 + lane] = lrow;

  // partial O (unnormalized, bf16)
  u16* Od = Op + (size_t)khalf * MROWS * EE;
#pragma unroll
  for (int r = 0; r < 4; ++r) {
    const size_t row = (size_t)(b * SS + q0 + quad * 4 + r) * EE + h * DD;
#pragma unroll
    for (int nd = 0; nd < 4; ++nd) {
      const int d = nd * 16 + l16;
      Od[row + d] = f2bf(oacc[nd][r]);
    }
  }
}

// ---------------- combine: oh = (O0+O1) / (l0+l1) ----------------
__global__ __launch_bounds__(256) void attn_combine(
    const u16* __restrict__ Op, const float* __restrict__ lp, u16* __restrict__ oh) {
  const int t = blockIdx.x * 256 + threadIdx.x;   // 524288 threads
  const int token = t >> 7, col0 = (t & 127) * 8;
  const int b = token >> 11, q = token & (SS - 1), h = col0 >> 6;
  const int bh = b * 16 + h;
  const float l0 = lp[(size_t)bh * SS + q];
  const float l1 = lp[(size_t)(BB * HH * SS) + (size_t)bh * SS + q];
  const float inv = 1.0f / (l0 + l1);
  const size_t off = (size_t)token * EE + col0;
  const uint4 a = *(const uint4*)&Op[off];
  const uint4 c = *(const uint4*)&Op[(size_t)MROWS * EE + off];
  uint4 r;
  const uint32_t au[4] = {a.x, a.y, a.z, a.w};
  const uint32_t cu[4] = {c.x, c.y, c.z, c.w};
  uint32_t ru[4];
#pragma unroll
  for (int i = 0; i < 4; ++i) {
    const float lo = (__uint_as_float(au[i] << 16) + __uint_as_float(cu[i] << 16)) * inv;
    const float hi = (__uint_as_float(au[i] & 0xFFFF0000u) + __uint_as_float(cu[i] & 0xFFFF0000u)) * inv;
    ru[i] = cvtpk_bf16(lo, hi);
  }
  r.x = ru[0]; r.y = ru[1]; r.z = ru[2]; r.w = ru[3];
  *(uint4*)&oh[off] = r;
}

// ---------------- output projection: single-pass bf16, 128x64, BK=64 --------
__global__ __launch_bounds__(256) void gemm_out(
    const u16* __restrict__ Ab, const u16* __restrict__ Bb,
    const float* __restrict__ bias, float* __restrict__ Cout) {
  __shared__ alignas(16) u16 sA[128 * 64];
  __shared__ alignas(16) u16 sB[64 * 64];
  const int rowBase = blockIdx.y * 128;
  const int colBase = blockIdx.x * 64;
  const int tid = threadIdx.x;
  const int lane = tid & 63, w = tid >> 6;
  const int quad = lane >> 4, l16 = lane & 15;
  const int wr = w >> 1, wc = w & 1;

  size_t aSrc[4]; u16* aDst[4];
  size_t bSrc[2]; u16* bDst[2];
#pragma unroll
  for (int j = 0; j < 4; ++j) {
    const int c = tid + j * 256;
    const int row = c >> 3, sl = c & 7;
    aSrc[j] = (size_t)(rowBase + row) * KDIM + ((sl ^ (row & 7)) * 8);
    aDst[j] = &sA[c * 8];
  }
#pragma unroll
  for (int j = 0; j < 2; ++j) {
    const int c = tid + j * 256;
    const int row = c >> 3, sl = c & 7;
    bSrc[j] = (size_t)(colBase + row) * KDIM + ((sl ^ (row & 7)) * 8);
    bDst[j] = &sB[c * 8];
  }

  f32x4 acc[4][2];
#pragma unroll
  for (int mi = 0; mi < 4; ++mi)
#pragma unroll
    for (int ni = 0; ni < 2; ++ni)
#pragma unroll
      for (int e = 0; e < 4; ++e) acc[mi][ni][e] = 0.f;

  const int arow = wr * 64 + l16, brow = wc * 32 + l16;

  for (int k0 = 0; k0 < KDIM; k0 += 64) {
    __syncthreads();
#pragma unroll
    for (int j = 0; j < 4; ++j) cp16(Ab + aSrc[j] + k0, aDst[j]);
#pragma unroll
    for (int j = 0; j < 2; ++j) cp16(Bb + bSrc[j] + k0, bDst[j]);
    __syncthreads();
#pragma unroll
    for (int h = 0; h < 2; ++h) {
      bf16x8 af[4], bf[2];
#pragma unroll
      for (int i = 0; i < 4; ++i) {
        const int ar = arow + i * 16;
        af[i] = *(const bf16x8*)&sA[ar * 64 + (((h * 4 + quad) ^ (ar & 7)) << 3)];
      }
#pragma unroll
      for (int i = 0; i < 2; ++i) {
        const int br = brow + i * 16;
        bf[i] = *(const bf16x8*)&sB[br * 64 + (((h * 4 + quad) ^ (br & 7)) << 3)];
      }
#pragma unroll
      for (int mi = 0; mi < 4; ++mi)
#pragma unroll
        for (int ni = 0; ni < 2; ++ni)
          acc[mi][ni] = mfma16(af[mi], bf[ni], acc[mi][ni]);
    }
  }

#pragma unroll
  for (int mi = 0; mi < 4; ++mi) {
    const int rb = rowBase + wr * 64 + mi * 16 + quad * 4;
#pragma unroll
    for (int ni = 0; ni < 2; ++ni) {
      const int col = colBase + wc * 32 + ni * 16 + l16;
      const float bb = bias[col];
#pragma unroll
      for (int r = 0; r < 4; ++r)
        Cout[(size_t)(rb + r) * NDIM + col] = acc[mi][ni][r] + bb;
    }
  }
}

// ---------------- host launch ----------------
extern "C" void kernel_launch(void* const* d_in, const int* in_sizes, int n_in,
                              void* d_out, int out_size, void* d_ws, size_t ws_size,
                              hipStream_t stream) {
  const float* q    = (const float*)d_in[0];
  const float* k    = (const float*)d_in[1];
  const float* v    = (const float*)d_in[2];
  const int*   mask = (const int*)d_in[3];
  const float* Wq = (const float*)d_in[4];
  const float* bq = (const float*)d_in[5];
  const float* Wk = (const float*)d_in[6];
  const float* bk = (const float*)d_in[7];
  const float* Wv = (const float*)d_in[8];
  const float* bv = (const float*)d_in[9];
  const float* Wo = (const float*)d_in[10];
  const float* bo = (const float*)d_in[11];
  float* out = (float*)d_out;
  char* ws = (char*)d_ws;
  constexpr size_t MB = 1024 * 1024;
  u16* qb  = (u16*)(ws + 0 * MB);
  u16* kb  = (u16*)(ws + 8 * MB);
  u16* vb  = (u16*)(ws + 16 * MB);
  u16* wqb = (u16*)(ws + 24 * MB);
  u16* wkb = (u16*)(ws + 26 * MB);
  u16* wvb = (u16*)(ws + 28 * MB);
  u16* wob = (u16*)(ws + 30 * MB);
  u16* Qp  = (u16*)(ws + 32 * MB);
  u16* Kp  = (u16*)(ws + 40 * MB);
  u16* Vtg = (u16*)(ws + 48 * MB);   // V^T head-major, pi-permuted keys
  u16* oh  = (u16*)(ws + 56 * MB);
  float* csT = (float*)(ws + 64 * MB);   // 1 MB
  u16* Op  = (u16*)(ws + 66 * MB);       // 2 x 8 MB partial O
  float* lp = (float*)(ws + 82 * MB);    // 2 x 256 KB partial l

  prep_cast<<<16896, 256, 0, stream>>>(q, k, v, Wq, Wk, Wv, Wo,
                                       qb, kb, vb, wqb, wkb, wvb, wob, csT);
  gemm_qkv<<<dim3(8, 96), 256, 0, stream>>>(qb, kb, vb, wqb, wkb, wvb,
                                            bq, bk, bv, Qp, Kp, Vtg, csT);
  attn_kernel<<<dim3(32, 32), 512, 0, stream>>>(Qp, Kp, Vtg, mask, Op, lp);
  attn_combine<<<2048, 256, 0, stream>>>(Op, lp, oh);
  gemm_out<<<dim3(16, 32), 256, 0, stream>>>(oh, wob, bo, out);
}